// Round 1
// baseline (82.305 us; speedup 1.0000x reference)
//
#include <hip/hip_runtime.h>

// SymmetricLoss: out = mean over 2M pairs of sqrt((tx+fx)^2 + (ty-fy)^2 + (tz-fz)^2)
// vt: 4M x 3 float32 (48 MB), mapping_table: 2M x 2 int32 (as delivered by harness).

#ifndef GRID_BLOCKS
#define GRID_BLOCKS 2048
#endif

__global__ __launch_bounds__(256) void symloss_partial_kernel(
    const float* __restrict__ vt,
    const int* __restrict__ map2,   // int2 pairs
    float* __restrict__ partials,
    int n_pairs)
{
    int tid = blockIdx.x * blockDim.x + threadIdx.x;
    int stride = gridDim.x * blockDim.x;
    float lsum = 0.0f;
    for (int i = tid; i < n_pairs; i += stride) {
        int2 ij = ((const int2*)map2)[i];
        int a = ij.x * 3;
        int b = ij.y * 3;
        float fx = vt[a + 0];
        float fy = vt[a + 1];
        float fz = vt[a + 2];
        float tx = vt[b + 0];
        float ty = vt[b + 1];
        float tz = vt[b + 2];
        float dx = tx + fx;   // NOTE: reference uses + for x
        float dy = ty - fy;
        float dz = tz - fz;
        lsum += sqrtf(dx * dx + dy * dy + dz * dz);
    }
    // 64-lane wave reduction
    #pragma unroll
    for (int off = 32; off > 0; off >>= 1)
        lsum += __shfl_down(lsum, off, 64);

    __shared__ float wsums[4];  // 256 threads = 4 waves
    int lane = threadIdx.x & 63;
    int wid  = threadIdx.x >> 6;
    if (lane == 0) wsums[wid] = lsum;
    __syncthreads();
    if (threadIdx.x == 0) {
        float s = 0.0f;
        #pragma unroll
        for (int w = 0; w < 4; ++w) s += wsums[w];
        partials[blockIdx.x] = s;
    }
}

__global__ __launch_bounds__(256) void symloss_finish_kernel(
    const float* __restrict__ partials,
    int n,
    float* __restrict__ out,
    float inv_npairs)
{
    double s = 0.0;
    for (int i = threadIdx.x; i < n; i += blockDim.x)
        s += (double)partials[i];
    #pragma unroll
    for (int off = 32; off > 0; off >>= 1)
        s += __shfl_down(s, off, 64);

    __shared__ double wsums[4];
    int lane = threadIdx.x & 63;
    int wid  = threadIdx.x >> 6;
    if (lane == 0) wsums[wid] = s;
    __syncthreads();
    if (threadIdx.x == 0) {
        double t = 0.0;
        #pragma unroll
        for (int w = 0; w < 4; ++w) t += wsums[w];
        out[0] = (float)(t * (double)inv_npairs);
    }
}

extern "C" void kernel_launch(void* const* d_in, const int* in_sizes, int n_in,
                              void* d_out, int out_size, void* d_ws, size_t ws_size,
                              hipStream_t stream) {
    const float* vt  = (const float*)d_in[0];
    const int* map2  = (const int*)d_in[1];
    float* out       = (float*)d_out;
    float* partials  = (float*)d_ws;   // GRID_BLOCKS floats

    int n_pairs = in_sizes[1] / 2;     // mapping_table flat count = 2*N_PAIRS

    symloss_partial_kernel<<<GRID_BLOCKS, 256, 0, stream>>>(vt, map2, partials, n_pairs);
    symloss_finish_kernel<<<1, 256, 0, stream>>>(partials, GRID_BLOCKS, out,
                                                 1.0f / (float)n_pairs);
}

// Round 2
// 80.866 us; speedup vs baseline: 1.0178x; 1.0178x over previous
//
#include <hip/hip_runtime.h>

// SymmetricLoss: out = mean over 2M pairs of sqrt((tx+fx)^2 + (ty-fy)^2 + (tz-fz)^2)
// vt: 4M x 3 float32 (48 MB), mapping_table delivered as int32 pairs.
//
// Bound by L2-miss line traffic from random gathers (251 MB @ ~3.3 TB/s).
// This version maximizes memory-level parallelism: 4 pairs (8 vertex gathers)
// in flight per thread, single shot, nontemporal index loads.

typedef int int4v __attribute__((ext_vector_type(4)));

#define PPT 4  // pairs per thread

__global__ __launch_bounds__(256) void symloss_partial_kernel(
    const float* __restrict__ vt,
    const int* __restrict__ map2,
    float* __restrict__ partials,
    int n_pairs)
{
    int t = blockIdx.x * blockDim.x + threadIdx.x;
    long i0 = (long)t * PPT;
    float lsum = 0.0f;

    if (i0 + PPT <= n_pairs) {
        // two 16B nontemporal loads: indices for 4 pairs (32B/lane, coalesced)
        const int4v* mp = (const int4v*)(map2 + i0 * 2);
        int4v m01 = __builtin_nontemporal_load(mp);
        int4v m23 = __builtin_nontemporal_load(mp + 1);

        int a0 = m01.x * 3, b0 = m01.y * 3;
        int a1 = m01.z * 3, b1 = m01.w * 3;
        int a2 = m23.x * 3, b2 = m23.y * 3;
        int a3 = m23.z * 3, b3 = m23.w * 3;

        // 8 independent 12B gathers — all in flight together
        float fx0 = vt[a0], fy0 = vt[a0 + 1], fz0 = vt[a0 + 2];
        float tx0 = vt[b0], ty0 = vt[b0 + 1], tz0 = vt[b0 + 2];
        float fx1 = vt[a1], fy1 = vt[a1 + 1], fz1 = vt[a1 + 2];
        float tx1 = vt[b1], ty1 = vt[b1 + 1], tz1 = vt[b1 + 2];
        float fx2 = vt[a2], fy2 = vt[a2 + 1], fz2 = vt[a2 + 2];
        float tx2 = vt[b2], ty2 = vt[b2 + 1], tz2 = vt[b2 + 2];
        float fx3 = vt[a3], fy3 = vt[a3 + 1], fz3 = vt[a3 + 2];
        float tx3 = vt[b3], ty3 = vt[b3 + 1], tz3 = vt[b3 + 2];

        float dx0 = tx0 + fx0, dy0 = ty0 - fy0, dz0 = tz0 - fz0;
        float dx1 = tx1 + fx1, dy1 = ty1 - fy1, dz1 = tz1 - fz1;
        float dx2 = tx2 + fx2, dy2 = ty2 - fy2, dz2 = tz2 - fz2;
        float dx3 = tx3 + fx3, dy3 = ty3 - fy3, dz3 = tz3 - fz3;

        lsum  = sqrtf(dx0 * dx0 + dy0 * dy0 + dz0 * dz0);
        lsum += sqrtf(dx1 * dx1 + dy1 * dy1 + dz1 * dz1);
        lsum += sqrtf(dx2 * dx2 + dy2 * dy2 + dz2 * dz2);
        lsum += sqrtf(dx3 * dx3 + dy3 * dy3 + dz3 * dz3);
    } else {
        // tail (unused when n_pairs % PPT == 0, kept for safety)
        for (long i = i0; i < n_pairs; ++i) {
            int2 ij = ((const int2*)map2)[i];
            int a = ij.x * 3, b = ij.y * 3;
            float dx = vt[b] + vt[a];
            float dy = vt[b + 1] - vt[a + 1];
            float dz = vt[b + 2] - vt[a + 2];
            lsum += sqrtf(dx * dx + dy * dy + dz * dz);
        }
    }

    // 64-lane wave reduction
    #pragma unroll
    for (int off = 32; off > 0; off >>= 1)
        lsum += __shfl_down(lsum, off, 64);

    __shared__ float wsums[4];
    int lane = threadIdx.x & 63;
    int wid  = threadIdx.x >> 6;
    if (lane == 0) wsums[wid] = lsum;
    __syncthreads();
    if (threadIdx.x == 0) {
        float s = 0.0f;
        #pragma unroll
        for (int w = 0; w < 4; ++w) s += wsums[w];
        partials[blockIdx.x] = s;
    }
}

__global__ __launch_bounds__(256) void symloss_finish_kernel(
    const float* __restrict__ partials,
    int n,
    float* __restrict__ out,
    float inv_npairs)
{
    double s = 0.0;
    for (int i = threadIdx.x; i < n; i += blockDim.x)
        s += (double)partials[i];
    #pragma unroll
    for (int off = 32; off > 0; off >>= 1)
        s += __shfl_down(s, off, 64);

    __shared__ double wsums[4];
    int lane = threadIdx.x & 63;
    int wid  = threadIdx.x >> 6;
    if (lane == 0) wsums[wid] = s;
    __syncthreads();
    if (threadIdx.x == 0) {
        double t = 0.0;
        #pragma unroll
        for (int w = 0; w < 4; ++w) t += wsums[w];
        out[0] = (float)(t * (double)inv_npairs);
    }
}

extern "C" void kernel_launch(void* const* d_in, const int* in_sizes, int n_in,
                              void* d_out, int out_size, void* d_ws, size_t ws_size,
                              hipStream_t stream) {
    const float* vt  = (const float*)d_in[0];
    const int* map2  = (const int*)d_in[1];
    float* out       = (float*)d_out;
    float* partials  = (float*)d_ws;

    int n_pairs = in_sizes[1] / 2;
    int threads_needed = (n_pairs + PPT - 1) / PPT;
    int n_blocks = (threads_needed + 255) / 256;

    symloss_partial_kernel<<<n_blocks, 256, 0, stream>>>(vt, map2, partials, n_pairs);
    symloss_finish_kernel<<<1, 256, 0, stream>>>(partials, n_blocks, out,
                                                 1.0f / (float)n_pairs);
}